// Round 1
// baseline (1706.360 us; speedup 1.0000x reference)
//
#include <hip/hip_runtime.h>

#define SS 2048
#define DD 64
#define TQ 64
#define NCHUNK (SS / 64)

typedef __attribute__((ext_vector_type(8))) short          short8;
typedef __attribute__((ext_vector_type(8))) __bf16         bf16x8;
typedef __attribute__((ext_vector_type(4))) float          float4v;
typedef __attribute__((ext_vector_type(4))) unsigned short ushort4v;

__device__ __forceinline__ unsigned short f2bf(float x) {
    unsigned u = __float_as_uint(x);
    u += 0x7fffu + ((u >> 16) & 1u);   // round-to-nearest-even (same as before)
    return (unsigned short)(u >> 16);
}

__device__ __forceinline__ bf16x8 ld_frag(const unsigned short* p) {
    return __builtin_bit_cast(bf16x8, *(const short8*)p);
}

// ---------- prep: K -> bf16 row-major [s][d]; V -> bf16 transposed [d][s] ----------
__global__ __launch_bounds__(256) void prep_kv(
    const float* __restrict__ K, const float* __restrict__ V,
    unsigned short* __restrict__ Kb, unsigned short* __restrict__ Vtb)
{
    const int tid = threadIdx.x;
    const int bh  = blockIdx.x;
    const int ch  = blockIdx.y;

    const float* Kc = K + ((size_t)bh * SS + ch * 64) * DD;
    unsigned short* Kbc = Kb + ((size_t)bh * SS + ch * 64) * DD;
    #pragma unroll
    for (int it = 0; it < 4; ++it) {
        int e4 = it * 256 + tid;
        float4v v = *(const float4v*)(Kc + e4 * 4);
        ushort4v h;
        h[0] = f2bf(v[0]); h[1] = f2bf(v[1]); h[2] = f2bf(v[2]); h[3] = f2bf(v[3]);
        *(ushort4v*)(Kbc + e4 * 4) = h;
    }

    // V transpose: lane-major in s so each 2B write stream is 128B contiguous
    const float* Vc = V + ((size_t)bh * SS + ch * 64) * DD;
    unsigned short* Vtc = Vtb + (size_t)bh * DD * SS + ch * 64;
    #pragma unroll
    for (int it = 0; it < 4; ++it) {
        int e4 = it * 256 + tid;
        int s  = e4 & 63;
        int g  = e4 >> 6;
        float4v v = *(const float4v*)(Vc + s * DD + g * 4);
        Vtc[(g * 4 + 0) * SS + s] = f2bf(v[0]);
        Vtc[(g * 4 + 1) * SS + s] = f2bf(v[1]);
        Vtc[(g * 4 + 2) * SS + s] = f2bf(v[2]);
        Vtc[(g * 4 + 3) * SS + s] = f2bf(v[3]);
    }
}

// ---------- main: barrier-free, fragments loaded straight from L2-resident bf16 ----------
__global__ __launch_bounds__(256, 4) void attn_fused(
    const float* __restrict__ Q, const unsigned short* __restrict__ Kb,
    const unsigned short* __restrict__ Vtb, const int* __restrict__ mask,
    float* __restrict__ outp, float* __restrict__ pattn)
{
    // per-wave 16x64 bf16 P-transpose tile, XOR-swizzled (col ^ (row&7)<<3) so
    // ds_read_b128 of a row-slice is conflict-free. Wave-local only -> no barrier.
    __shared__ unsigned short Pw[4 * 16 * 64];

    const int tid  = threadIdx.x;
    const int w    = tid >> 6;
    const int lane = tid & 63;
    const int lq   = lane & 15;
    const int quad = lane >> 4;

    const int bh = blockIdx.x;       // bh fastest-varying -> same-bh blocks share XCD
    const int b  = bh >> 4;
    const int q0 = blockIdx.y * TQ;

    const unsigned short* Kg = Kb  + (size_t)bh * SS * DD;
    const unsigned short* Vg = Vtb + (size_t)bh * DD * SS;
    const int* mg = mask + b * SS;

    // ---- Q A-fragments (rows w*16+lq, k = quad*8 / 32+quad*8), pre-scaled by 0.125 ----
    bf16x8 a0, a1;
    {
        const float* Qg = Q + ((size_t)bh * SS + q0 + w * 16 + lq) * DD + quad * 8;
        float4v q00 = *(const float4v*)(Qg);
        float4v q01 = *(const float4v*)(Qg + 4);
        float4v q10 = *(const float4v*)(Qg + 32);
        float4v q11 = *(const float4v*)(Qg + 36);
        short8 s0, s1;
        #pragma unroll
        for (int j = 0; j < 4; ++j) {
            s0[j]     = (short)f2bf(q00[j] * 0.125f);
            s0[j + 4] = (short)f2bf(q01[j] * 0.125f);
            s1[j]     = (short)f2bf(q10[j] * 0.125f);
            s1[j + 4] = (short)f2bf(q11[j] * 0.125f);
        }
        a0 = __builtin_bit_cast(bf16x8, s0);
        a1 = __builtin_bit_cast(bf16x8, s1);
    }

    float m_r[4], l_r[4];
    #pragma unroll
    for (int r = 0; r < 4; ++r) { m_r[r] = -INFINITY; l_r[r] = 0.0f; }

    // =================== PASS 1: row max & sum (no LDS, no barriers) ===================
    for (int c = 0; c < NCHUNK; ++c) {
        const unsigned short* Kc = Kg + (size_t)(c * 64) * DD;
        bf16x8 kb0[4], kb1[4];
        #pragma unroll
        for (int t = 0; t < 4; ++t) {
            kb0[t] = ld_frag(Kc + (t * 16 + lq) * DD + quad * 8);
            kb1[t] = ld_frag(Kc + (t * 16 + lq) * DD + 32 + quad * 8);
        }
        float4v sc[4];
        #pragma unroll
        for (int t = 0; t < 4; ++t) {
            float bias = (mg[c * 64 + t * 16 + lq] == 0) ? -1e9f : 0.0f;
            float4v acc = {bias, bias, bias, bias};
            acc = __builtin_amdgcn_mfma_f32_16x16x32_bf16(a0, kb0[t], acc, 0, 0, 0);
            acc = __builtin_amdgcn_mfma_f32_16x16x32_bf16(a1, kb1[t], acc, 0, 0, 0);
            sc[t] = acc;
        }
        #pragma unroll
        for (int r = 0; r < 4; ++r) {
            float mx = fmaxf(fmaxf(sc[0][r], sc[1][r]), fmaxf(sc[2][r], sc[3][r]));
            float mn = fmaxf(m_r[r], mx);
            float sum = __expf(sc[0][r] - mn) + __expf(sc[1][r] - mn)
                      + __expf(sc[2][r] - mn) + __expf(sc[3][r] - mn);
            l_r[r] = l_r[r] * __expf(m_r[r] - mn) + sum;
            m_r[r] = mn;
        }
    }

    // butterfly reduce (m,l) across the 16 lanes holding one row's columns
    #pragma unroll
    for (int r = 0; r < 4; ++r) {
        float m = m_r[r], l = l_r[r];
        #pragma unroll
        for (int off = 1; off < 16; off <<= 1) {
            float mo = __shfl_xor(m, off, 64);
            float lo = __shfl_xor(l, off, 64);
            float mn = fmaxf(m, mo);
            l = l * __expf(m - mn) + lo * __expf(mo - mn);
            m = mn;
        }
        m_r[r] = m;
        l_r[r] = 1.0f / l;   // keep reciprocal
    }

    // =================== PASS 2: p, p_attn stores, PV (no barriers) ===================
    float4v oacc[4];
    #pragma unroll
    for (int t = 0; t < 4; ++t) oacc[t] = (float4v){0.f, 0.f, 0.f, 0.f};

    unsigned short* pw = Pw + w * 16 * 64;
    const int rswz = (lq & 7) << 3;

    for (int c = 0; c < NCHUNK; ++c) {
        const unsigned short* Kc = Kg + (size_t)(c * 64) * DD;
        bf16x8 kb0[4], kb1[4];
        #pragma unroll
        for (int t = 0; t < 4; ++t) {
            kb0[t] = ld_frag(Kc + (t * 16 + lq) * DD + quad * 8);
            kb1[t] = ld_frag(Kc + (t * 16 + lq) * DD + 32 + quad * 8);
        }
        float4v sc[4];
        #pragma unroll
        for (int t = 0; t < 4; ++t) {
            float bias = (mg[c * 64 + t * 16 + lq] == 0) ? -1e9f : 0.0f;
            float4v acc = {bias, bias, bias, bias};
            acc = __builtin_amdgcn_mfma_f32_16x16x32_bf16(a0, kb0[t], acc, 0, 0, 0);
            acc = __builtin_amdgcn_mfma_f32_16x16x32_bf16(a1, kb1[t], acc, 0, 0, 0);
            sc[t] = acc;
        }

        // V B-fragments straight from global (L2-resident); issued under softmax VALU
        bf16x8 vb[4][2];
        #pragma unroll
        for (int t = 0; t < 4; ++t) {
            #pragma unroll
            for (int ks = 0; ks < 2; ++ks) {
                vb[t][ks] = ld_frag(Vg + (size_t)(t * 16 + lq) * SS
                                       + c * 64 + ks * 32 + quad * 8);
            }
        }

        float* pg = pattn + ((size_t)bh * SS + (q0 + w * 16 + quad * 4)) * SS + c * 64;
        #pragma unroll
        for (int t = 0; t < 4; ++t) {
            #pragma unroll
            for (int r = 0; r < 4; ++r) {
                float p = __expf(sc[t][r] - m_r[r]) * l_r[r];
                pg[(size_t)r * SS + t * 16 + lq] = p;
                int row = quad * 4 + r;
                pw[row * 64 + ((t * 16 + lq) ^ ((row & 7) << 3))] = f2bf(p);
            }
        }
        asm volatile("" ::: "memory");  // keep ds_reads ordered after the writes (wave-local, DS is in-order)

        #pragma unroll
        for (int ks = 0; ks < 2; ++ks) {
            bf16x8 pa = ld_frag(pw + lq * 64 + ((ks * 32 + quad * 8) ^ rswz));
            #pragma unroll
            for (int t = 0; t < 4; ++t) {
                oacc[t] = __builtin_amdgcn_mfma_f32_16x16x32_bf16(pa, vb[t][ks], oacc[t], 0, 0, 0);
            }
        }
    }

    // ---- store out ----
    float* og = outp + ((size_t)bh * SS + (q0 + w * 16 + quad * 4)) * DD;
    #pragma unroll
    for (int t = 0; t < 4; ++t) {
        #pragma unroll
        for (int r = 0; r < 4; ++r) {
            og[(size_t)r * DD + t * 16 + lq] = oacc[t][r];
        }
    }
}

extern "C" void kernel_launch(void* const* d_in, const int* in_sizes, int n_in,
                              void* d_out, int out_size, void* d_ws, size_t ws_size,
                              hipStream_t stream) {
    const float* Q    = (const float*)d_in[0];
    const float* K    = (const float*)d_in[1];
    const float* V    = (const float*)d_in[2];
    const int*   mask = (const int*)d_in[3];
    float* outp  = (float*)d_out;
    float* pattn = outp + (size_t)4 * 16 * 2048 * 64;   // out is first in tuple

    // workspace: Kb (16.78 MB) + Vtb (16.78 MB) bf16
    unsigned short* Kb  = (unsigned short*)d_ws;
    unsigned short* Vtb = Kb + (size_t)64 * SS * DD;

    dim3 pgrid(64, NCHUNK);
    prep_kv<<<pgrid, 256, 0, stream>>>(K, V, Kb, Vtb);

    dim3 grid(64, SS / TQ);   // (bh, q-tile)
    attn_fused<<<grid, 256, 0, stream>>>(Q, Kb, Vtb, mask, outp, pattn);
}